// Round 1
// baseline (330.546 us; speedup 1.0000x reference)
//
#include <hip/hip_runtime.h>

#define NS 16
#define N_ATOMS 2000
#define NB 2000
#define NA 4000
#define NV 400000
#define NT 6000
#define NI 1000

#define OUT_S 819001
#define OFF_EB 0
#define OFF_EA 2000
#define OFF_EUB 6000
#define OFF_EV 6001
#define OFF_EC 406001
#define OFF_ET 806001
#define OFF_EI 812001
#define OFF_F 813001

#define CHARGE_TENTH 1.8222615f

// ---------------------------------------------------------------------------
// Zero the Force region + E_ub slot for every sample (harness poisons d_out
// once; we accumulate forces atomically so they must start at zero each call).
__global__ void init_kernel(float* __restrict__ out) {
    int idx = blockIdx.x * blockDim.x + threadIdx.x;
    const int per_s = N_ATOMS * 3 + 1;
    const int total = NS * per_s;
    if (idx >= total) return;
    int s = idx / per_s;
    int r = idx - s * per_s;
    if (r == 0)
        out[(size_t)s * OUT_S + OFF_EUB] = 0.0f;
    else
        out[(size_t)s * OUT_S + OFF_F + (r - 1)] = 0.0f;
}

// ---------------------------------------------------------------------------
// Bond + angle + torsion + imptors: energies written directly, forces via
// direct global atomics (only ~2.1M lane-atomics total).
__global__ void bonded_kernel(
    const float* __restrict__ lb,    // length_bond   (NS,NB)
    const float* __restrict__ th,    // theta_angle   (NS,NA)
    const float* __restrict__ sc,    // sin_cos_torsion (NS,NT,8)
    const float* __restrict__ c2i,   // cos2_imptors  (NS,NI)
    const float* __restrict__ pb,    // paras_bond    (NB,2)
    const float* __restrict__ pa,    // paras_angle   (NA,2)
    const float* __restrict__ pt,    // paras_torsion (NT,4)
    const float* __restrict__ pim,   // paras_imptors (NI,1)
    const float* __restrict__ dlb,   // dlength_bond  (NS,NB,6)
    const float* __restrict__ dth,   // dtheta_angle  (NS,NA,9)
    const float* __restrict__ dtt,   // dtheta_torsion(NS,NT,12)
    const float* __restrict__ dc2,   // dcos2_imptors (NS,NI,12)
    const int*   __restrict__ bidx,  // bond_index    (NB,2)
    const int*   __restrict__ aidx,  // angle_index   (NA,3)
    const int*   __restrict__ tidx,  // torsion_index (NT,4)
    const int*   __restrict__ iidx,  // imptors_index (NI,4)
    float* __restrict__ out)
{
    int t = blockIdx.x * blockDim.x + threadIdx.x;
    int s = blockIdx.y;
    float* F = out + (size_t)s * OUT_S + OFF_F;

    if (t < NB) {
        int b = t;
        float K  = pb[2 * b] * 100.0f;
        float r0 = pb[2 * b + 1];
        float d  = lb[s * NB + b] - r0;
        out[(size_t)s * OUT_S + OFF_EB + b] = K * d * d;
        float g = 2.0f * K * d;
        const float* dd = dlb + ((size_t)s * NB + b) * 6;
        #pragma unroll
        for (int p = 0; p < 2; ++p) {
            int a = bidx[2 * b + p] * 3;
            atomicAdd(&F[a + 0], dd[3 * p + 0] * g);
            atomicAdd(&F[a + 1], dd[3 * p + 1] * g);
            atomicAdd(&F[a + 2], dd[3 * p + 2] * g);
        }
    } else if (t < NB + NA) {
        int a = t - NB;
        float Ka  = pa[2 * a] * 10.0f;
        float th0 = pa[2 * a + 1] * 0.31415926535f;  // pi/10
        float da  = th[s * NA + a] - th0;
        out[(size_t)s * OUT_S + OFF_EA + a] = Ka * da * da;
        float g = 2.0f * Ka * da;
        const float* dd = dth + ((size_t)s * NA + a) * 9;
        #pragma unroll
        for (int p = 0; p < 3; ++p) {
            int at = aidx[3 * a + p] * 3;
            atomicAdd(&F[at + 0], dd[3 * p + 0] * g);
            atomicAdd(&F[at + 1], dd[3 * p + 1] * g);
            atomicAdd(&F[at + 2], dd[3 * p + 2] * g);
        }
    } else if (t < NB + NA + NT) {
        int tt = t - (NB + NA);
        const float* s8 = sc + ((size_t)s * NT + tt) * 8;
        const float* p4 = pt + (size_t)tt * 4;
        float E = 0.0f, Sf = 0.0f;
        #pragma unroll
        for (int n = 0; n < 4; ++n) {
            float pn = p4[n];
            E  += s8[2 * n + 1] * pn;             // cos terms
            Sf += s8[2 * n]     * pn * (float)(n + 1); // sin * coeff
        }
        out[(size_t)s * OUT_S + OFF_ET + tt] = E;
        float g = -Sf;
        const float* dd = dtt + ((size_t)s * NT + tt) * 12;
        #pragma unroll
        for (int p = 0; p < 4; ++p) {
            int at = tidx[4 * tt + p] * 3;
            atomicAdd(&F[at + 0], dd[3 * p + 0] * g);
            atomicAdd(&F[at + 1], dd[3 * p + 1] * g);
            atomicAdd(&F[at + 2], dd[3 * p + 2] * g);
        }
    } else if (t < NB + NA + NT + NI) {
        int ii = t - (NB + NA + NT);
        float ki = pim[ii];
        out[(size_t)s * OUT_S + OFF_EI + ii] = ki * (1.0f - c2i[s * NI + ii]);
        float g = -ki;
        const float* dd = dc2 + ((size_t)s * NI + ii) * 12;
        #pragma unroll
        for (int p = 0; p < 4; ++p) {
            int at = iidx[4 * ii + p] * 3;
            atomicAdd(&F[at + 0], dd[3 * p + 0] * g);
            atomicAdd(&F[at + 1], dd[3 * p + 1] * g);
            atomicAdd(&F[at + 2], dd[3 * p + 2] * g);
        }
    }
}

// ---------------------------------------------------------------------------
// vdw + charge: fused single pass over dlength_vdw; LDS force accumulation
// per (sample, v-chunk) block, one atomic flush per block.
#define VC 12500   // 32 chunks exactly cover NV=400000
#define VBLK 512

__global__ __launch_bounds__(VBLK) void vdw_kernel(
    const float* __restrict__ lv,   // length_vdw (NS,NV)
    const float* __restrict__ v14,  // vdw14 (NV)
    const float* __restrict__ q14,  // charge14 (NV)
    const float* __restrict__ pv,   // paras_vdw (N_ATOMS,2)
    const float* __restrict__ pc,   // paras_charge (N_ATOMS)
    const float* __restrict__ dlv,  // dlength_vdw (NS,NV,6)
    const int*   __restrict__ nb,   // nonbonded (2,NV)
    const int*   __restrict__ nbi,  // nonbonded_index (NV,2)
    float* __restrict__ out)
{
    __shared__ float fbuf[N_ATOMS * 3];
    int tid   = threadIdx.x;
    int s     = blockIdx.x;
    int chunk = blockIdx.y;

    for (int k = tid; k < N_ATOMS * 3; k += VBLK) fbuf[k] = 0.0f;
    __syncthreads();

    const int v0 = chunk * VC;
    const float* lvs = lv + (size_t)s * NV;
    float* outE = out + (size_t)s * OUT_S;

    for (int v = v0 + tid; v < v0 + VC; v += VBLK) {
        int i = nb[v];
        int j = nb[NV + v];
        float2 pvi = ((const float2*)pv)[i];
        float2 pvj = ((const float2*)pv)[j];
        float sigma = pvi.x + pvj.x;
        float eps   = pvi.y * pvj.y * 0.01f * v14[v];
        float r     = lvs[v];
        float rinv  = __builtin_amdgcn_rcpf(r);
        float r2inv = rinv * rinv;
        float sig2  = sigma * sigma;
        float sig6  = sig2 * sig2 * sig2;
        float r6inv = r2inv * r2inv * r2inv;
        float t     = sig6 * r6inv;
        float Ev    = eps * (t * t - 2.0f * t);
        float c1    = CHARGE_TENTH * pc[i];
        float c2    = CHARGE_TENTH * pc[j];
        float cc    = c1 * c2 * q14[v];
        float Ec    = cc * rinv;
        float fs    = 12.0f * eps * t * (1.0f - t) * rinv - cc * r2inv;

        outE[OFF_EV + v] = Ev;
        outE[OFF_EC + v] = Ec;

        const float2* dd = (const float2*)(dlv + ((size_t)s * NV + v) * 6);
        float2 d0 = dd[0];
        float2 d1 = dd[1];
        float2 d2 = dd[2];
        int2 aa = ((const int2*)nbi)[v];
        int b0 = aa.x * 3;
        int b1 = aa.y * 3;
        atomicAdd(&fbuf[b0 + 0], d0.x * fs);
        atomicAdd(&fbuf[b0 + 1], d0.y * fs);
        atomicAdd(&fbuf[b0 + 2], d1.x * fs);
        atomicAdd(&fbuf[b1 + 0], d1.y * fs);
        atomicAdd(&fbuf[b1 + 1], d2.x * fs);
        atomicAdd(&fbuf[b1 + 2], d2.y * fs);
    }
    __syncthreads();

    float* F = outE + OFF_F;
    for (int k = tid; k < N_ATOMS * 3; k += VBLK) {
        float val = fbuf[k];
        if (val != 0.0f) atomicAdd(&F[k], val);
    }
}

// ---------------------------------------------------------------------------
extern "C" void kernel_launch(void* const* d_in, const int* in_sizes, int n_in,
                              void* d_out, int out_size, void* d_ws, size_t ws_size,
                              hipStream_t stream) {
    const float* lb  = (const float*)d_in[0];   // length_bond
    const float* th  = (const float*)d_in[1];   // theta_angle
    const float* lv  = (const float*)d_in[2];   // length_vdw
    const float* sc  = (const float*)d_in[3];   // sin_cos_torsion
    const float* c2i = (const float*)d_in[4];   // cos2_imptors
    const float* v14 = (const float*)d_in[5];   // vdw14
    const float* q14 = (const float*)d_in[6];   // charge14
    const float* pb  = (const float*)d_in[7];   // paras_bond
    const float* pa  = (const float*)d_in[8];   // paras_angle
    const float* pv  = (const float*)d_in[9];   // paras_vdw
    const float* pc  = (const float*)d_in[10];  // paras_charge
    const float* pt  = (const float*)d_in[11];  // paras_torsion
    const float* pim = (const float*)d_in[12];  // paras_imptors
    const float* dlb = (const float*)d_in[13];  // dlength_bond
    const float* dth = (const float*)d_in[14];  // dtheta_angle
    const float* dlv = (const float*)d_in[15];  // dlength_vdw
    const float* dtt = (const float*)d_in[16];  // dtheta_torsion
    const float* dc2 = (const float*)d_in[17];  // dcos2_imptors
    const int* nb    = (const int*)d_in[18];    // nonbonded
    const int* bidx  = (const int*)d_in[19];    // bond_index
    const int* aidx  = (const int*)d_in[20];    // angle_index
    const int* nbi   = (const int*)d_in[21];    // nonbonded_index
    const int* tidx  = (const int*)d_in[22];    // torsion_index
    const int* iidx  = (const int*)d_in[23];    // imptors_index
    float* out = (float*)d_out;

    // 1) zero Force + E_ub
    {
        int total = NS * (N_ATOMS * 3 + 1);
        int blocks = (total + 255) / 256;
        init_kernel<<<blocks, 256, 0, stream>>>(out);
    }
    // 2) bonded terms
    {
        dim3 grid((NB + NA + NT + NI + 255) / 256, NS);
        bonded_kernel<<<grid, 256, 0, stream>>>(lb, th, sc, c2i, pb, pa, pt, pim,
                                                dlb, dth, dtt, dc2,
                                                bidx, aidx, tidx, iidx, out);
    }
    // 3) vdw + charge
    {
        dim3 grid(NS, NV / VC);
        vdw_kernel<<<grid, VBLK, 0, stream>>>(lv, v14, q14, pv, pc, dlv, nb, nbi, out);
    }
}